// Round 1
// baseline (38937.057 us; speedup 1.0000x reference)
//
#include <hip/hip_runtime.h>
#include <math.h>

// ESN recurrence: h_{k} = 0.99*h_{k-1} + 0.01*tanh(Win x_{k-1} + Wh h_{k-1}), k=1..8192
// out[k-101][0:2048] = h_k (k>=101), out[.][2048:2112] = x_{k-1}
//
// Design: latency-bound sequential scan. 128 persistent WGs (1/CU), Wh rows in
// VGPRs, per-step device-wide h broadcast via double-buffered global vector +
// per-WG monotonic flags (agent-scope atomics bypass the non-coherent per-XCD L2).

#define NWG        128
#define ROWS_PER_WG 16
#define T_STEPS    8192
#define WARMUP     100
#define RSIZE      2048
#define ISIZE      64
#define OUTCOLS    2112
#define FLAG_STRIDE 32   // ints -> 128B per slot, no false sharing

__global__ __launch_bounds__(256) void init_ws_kernel(int* flags, float* bufs) {
    int t = blockIdx.x * blockDim.x + threadIdx.x;
    if (t < NWG * FLAG_STRIDE) flags[t] = 0;   // step 0 "h_0 ready"
    if (t < 2 * RSIZE)         bufs[t]  = 0.0f; // h_0 = 0 (buf1 zeroed too, harmless)
}

__global__ __launch_bounds__(256) void xcopy_kernel(const float* __restrict__ x,
                                                    float* __restrict__ out) {
    int t = blockIdx.x * blockDim.x + threadIdx.x;
    if (t >= (T_STEPS - WARMUP) * ISIZE) return;
    int rowo = t >> 6;          // output row 0..8091
    int j    = t & 63;
    out[(size_t)rowo * OUTCOLS + RSIZE + j] = x[(size_t)(rowo + WARMUP) * ISIZE + j];
}

__global__ __launch_bounds__(256, 1) void esn_scan_kernel(
    const float* __restrict__ x,    // [8192][64]
    const float* __restrict__ Win,  // [2048][64]
    const float* __restrict__ Wh,   // [2048][2048]
    float* __restrict__ out,        // [8092][2112]
    int*   flags,                   // [NWG*FLAG_STRIDE]
    float* buf0, float* buf1)       // [2048] each, double-buffered h
{
    __shared__ float hs[RSIZE];     // staged h_{k-1}, bank-swizzled

    const int tid = threadIdx.x;    // 0..255
    const int wg  = blockIdx.x;     // 0..127
    const int r   = tid >> 4;       // row within WG, 0..15
    const int c   = tid & 15;       // 128-col chunk index, 0..15
    const int row = wg * ROWS_PER_WG + r;

    // One-time register-resident weights.
    const float4 winf = *(const float4*)(Win + (size_t)row * ISIZE + c * 4);
    float4 wh[32];
    const float4* whp = (const float4*)(Wh + (size_t)row * RSIZE + c * 128);
#pragma unroll
    for (int j = 0; j < 32; ++j) wh[j] = whp[j];

    float hcur = 0.0f;              // this row's h (all 16 c-lanes track it)

    int* myflag   = flags + wg  * FLAG_STRIDE;
    int* pollflag = flags + tid * FLAG_STRIDE;  // valid for tid < NWG

    for (int k = 1; k <= T_STEPS; ++k) {
        // ---- wait until every WG has published h_{k-1} ----
        if (tid < NWG) {
            while (__hip_atomic_load(pollflag, __ATOMIC_RELAXED,
                                     __HIP_MEMORY_SCOPE_AGENT) < k - 1) { }
        }
        __syncthreads();  // also protects hs from early overwrite

        // ---- stage h_{k-1} global -> LDS (swizzled: chunk (cc,jj) at rot (jj+cc)&31) ----
        const float* bufPrev = ((k - 1) & 1) ? buf1 : buf0;
#pragma unroll
        for (int s = 0; s < 8; ++s) {
            int idx = tid + s * 256;                    // 0..2047
            float v = __hip_atomic_load(bufPrev + idx, __ATOMIC_RELAXED,
                                        __HIP_MEMORY_SCOPE_AGENT);  // bypass stale L1/L2
            int cc = idx >> 7;
            int jj = (idx >> 2) & 31;
            int e  = idx & 3;
            hs[cc * 128 + (((jj + cc) & 31) << 2) + e] = v;
        }
        __syncthreads();

        // ---- y[row] = Win[row]·x_{k-1} + Wh[row]·h_{k-1} ----
        const float4 xv = *(const float4*)(x + (size_t)(k - 1) * ISIZE + c * 4);
        float part = winf.x * xv.x + winf.y * xv.y + winf.z * xv.z + winf.w * xv.w;
        const float* hrow = hs + c * 128;
#pragma unroll
        for (int j = 0; j < 32; ++j) {
            const float4 hv = *(const float4*)(hrow + (((j + c) & 31) << 2));
            part += wh[j].x * hv.x + wh[j].y * hv.y + wh[j].z * hv.z + wh[j].w * hv.w;
        }
        // butterfly over the 16 c-lanes (c = low 4 lane bits)
        part += __shfl_xor(part, 1);
        part += __shfl_xor(part, 2);
        part += __shfl_xor(part, 4);
        part += __shfl_xor(part, 8);

        hcur = 0.99f * hcur + 0.01f * tanhf(part);

        // ---- publish h_k ----
        float* bufCur = (k & 1) ? buf1 : buf0;
        if (c == 0) {
            __hip_atomic_store(bufCur + row, hcur, __ATOMIC_RELAXED,
                               __HIP_MEMORY_SCOPE_AGENT);  // write-through to L3
            if (k >= WARMUP + 1) {
                out[(size_t)(k - (WARMUP + 1)) * OUTCOLS + row] = hcur;
            }
        }
        __syncthreads();  // compiler drains vmcnt(0) before s_barrier -> stores complete
        if (tid == 0) {
            __hip_atomic_store(myflag, k, __ATOMIC_RELAXED,
                               __HIP_MEMORY_SCOPE_AGENT);
        }
    }
}

extern "C" void kernel_launch(void* const* d_in, const int* in_sizes, int n_in,
                              void* d_out, int out_size, void* d_ws, size_t ws_size,
                              hipStream_t stream) {
    const float* x   = (const float*)d_in[0];  // [8192*64]
    const float* Win = (const float*)d_in[1];  // [2048*64]
    const float* Wh  = (const float*)d_in[2];  // [2048*2048]
    float* out = (float*)d_out;                // [8092*2112]

    char* ws = (char*)d_ws;
    int*   flags = (int*)ws;                       // 16 KB
    float* bufs  = (float*)(ws + 16384);           // 2*2048 floats
    float* buf0  = bufs;
    float* buf1  = bufs + RSIZE;

    // init flags + h buffers (ws is poisoned 0xAA before every timed launch)
    init_ws_kernel<<<16, 256, 0, stream>>>(flags, bufs);

    // x-part of the output, independent of the recurrence
    {
        int n = (T_STEPS - WARMUP) * ISIZE;
        xcopy_kernel<<<(n + 255) / 256, 256, 0, stream>>>(x, out);
    }

    // the sequential scan: 128 persistent workgroups
    esn_scan_kernel<<<NWG, 256, 0, stream>>>(x, Win, Wh, out, flags, buf0, buf1);
}

// Round 2
// 26497.382 us; speedup vs baseline: 1.4695x; 1.4695x over previous
//
#include <hip/hip_runtime.h>
#include <math.h>

// ESN recurrence: h_k = 0.99*h_{k-1} + 0.01*tanh(Win x_{k-1} + Wh h_{k-1}), k=1..8192
// out[k-101][0:2048] = h_k (k>=101), out[.][2048:2112] = x_{k-1}
//
// R2: fused data+tag broadcast. Each row publishes one 8B word (tag<<32 | h bits);
// consumers poll the words directly. One store hop + one poll hop per step
// (R1 had store -> vmcnt drain -> flag store -> flag poll -> data load).
// Race-free via double-buffered tagged slots: a WG overwrites tag k (with k+2)
// only after seeing all tags k+1, which data-depend on every WG's reads of tag k.

#define NWG        128
#define ROWS_PER_WG 16
#define T_STEPS    8192
#define WARMUP     100
#define RSIZE      2048
#define ISIZE      64
#define OUTCOLS    2112

__global__ __launch_bounds__(256) void init_ws_kernel(unsigned long long* buf0,
                                                      unsigned long long* buf1) {
    int t = blockIdx.x * blockDim.x + threadIdx.x;
    if (t < RSIZE) {
        buf0[t] = 0ull;                      // (tag=0, h_0=0.0f)
        buf1[t] = 0xFFFFFFFF00000000ull;     // invalid tag — first valid write is tag 1
    }
}

__global__ __launch_bounds__(256) void xcopy_kernel(const float* __restrict__ x,
                                                    float* __restrict__ out) {
    int t = blockIdx.x * blockDim.x + threadIdx.x;
    if (t >= (T_STEPS - WARMUP) * ISIZE) return;
    int rowo = t >> 6;          // output row 0..8091
    int j    = t & 63;
    out[(size_t)rowo * OUTCOLS + RSIZE + j] = x[(size_t)(rowo + WARMUP) * ISIZE + j];
}

__global__ __launch_bounds__(256, 1) void esn_scan_kernel(
    const float* __restrict__ x,    // [8192][64]
    const float* __restrict__ Win,  // [2048][64]
    const float* __restrict__ Wh,   // [2048][2048]
    float* __restrict__ out,        // [8092][2112]
    unsigned long long* buf0,       // [2048] tagged h slots, even steps (incl. h_0)
    unsigned long long* buf1)       // [2048] tagged h slots, odd steps
{
    __shared__ float hs[RSIZE];     // staged h_{k-1}, bank-swizzled

    const int tid = threadIdx.x;    // 0..255
    const int wg  = blockIdx.x;     // 0..127
    const int r   = tid >> 4;       // row within WG, 0..15
    const int c   = tid & 15;       // 128-col chunk index, 0..15
    const int row = wg * ROWS_PER_WG + r;

    // One-time register-resident weights.
    const float4 winf = *(const float4*)(Win + (size_t)row * ISIZE + c * 4);
    float4 wh[32];
    const float4* whp = (const float4*)(Wh + (size_t)row * RSIZE + c * 128);
#pragma unroll
    for (int j = 0; j < 32; ++j) wh[j] = whp[j];

    float hcur = 0.0f;              // this row's h (all 16 c-lanes track it)

    for (int k = 1; k <= T_STEPS; ++k) {
        // ---- poll the tagged h_{k-1} words directly (no separate flag) ----
        const unsigned long long* bp = ((k - 1) & 1) ? buf1 : buf0;
        const unsigned expect = (unsigned)(k - 1);
        unsigned long long w[8];
        unsigned mask = 0xFFu;
        while (mask) {
#pragma unroll
            for (int s = 0; s < 8; ++s) {
                if (mask & (1u << s)) {
                    w[s] = __hip_atomic_load(bp + s * 256 + tid, __ATOMIC_RELAXED,
                                             __HIP_MEMORY_SCOPE_AGENT);
                }
            }
#pragma unroll
            for (int s = 0; s < 8; ++s) {
                if ((mask & (1u << s)) && (unsigned)(w[s] >> 32) == expect) {
                    mask &= ~(1u << s);
                }
            }
        }

        __syncthreads();  // previous step's LDS reads finished before overwrite

        // ---- stage h_{k-1} -> LDS (swizzle: chunk (cc,jj) at rot (jj+cc)&31) ----
#pragma unroll
        for (int s = 0; s < 8; ++s) {
            int idx = s * 256 + tid;                    // 0..2047
            int cc = idx >> 7;
            int jj = (idx >> 2) & 31;
            int e  = idx & 3;
            hs[cc * 128 + (((jj + cc) & 31) << 2) + e] = __uint_as_float((unsigned)w[s]);
        }
        __syncthreads();

        // ---- y[row] = Win[row]·x_{k-1} + Wh[row]·h_{k-1} ----
        const float4 xv = *(const float4*)(x + (size_t)(k - 1) * ISIZE + c * 4);
        float part = winf.x * xv.x + winf.y * xv.y + winf.z * xv.z + winf.w * xv.w;
        const float* hrow = hs + c * 128;
#pragma unroll
        for (int j = 0; j < 32; ++j) {
            const float4 hv = *(const float4*)(hrow + (((j + c) & 31) << 2));
            part += wh[j].x * hv.x + wh[j].y * hv.y + wh[j].z * hv.z + wh[j].w * hv.w;
        }
        // butterfly over the 16 c-lanes (c = low 4 lane bits)
        part += __shfl_xor(part, 1);
        part += __shfl_xor(part, 2);
        part += __shfl_xor(part, 4);
        part += __shfl_xor(part, 8);

        hcur = 0.99f * hcur + 0.01f * tanhf(part);

        // ---- publish (tag=k, h_k) as one atomic 8B word; write output row ----
        if (c == 0) {
            unsigned long long* bc = (k & 1) ? buf1 : buf0;
            unsigned long long wv = ((unsigned long long)(unsigned)k << 32)
                                  | (unsigned long long)__float_as_uint(hcur);
            __hip_atomic_store(bc + row, wv, __ATOMIC_RELAXED,
                               __HIP_MEMORY_SCOPE_AGENT);
            if (k >= WARMUP + 1) {
                out[(size_t)(k - (WARMUP + 1)) * OUTCOLS + row] = hcur;
            }
        }
        // no barrier needed here: next iteration's poll tolerates in-flight stores
    }
}

extern "C" void kernel_launch(void* const* d_in, const int* in_sizes, int n_in,
                              void* d_out, int out_size, void* d_ws, size_t ws_size,
                              hipStream_t stream) {
    const float* x   = (const float*)d_in[0];  // [8192*64]
    const float* Win = (const float*)d_in[1];  // [2048*64]
    const float* Wh  = (const float*)d_in[2];  // [2048*2048]
    float* out = (float*)d_out;                // [8092*2112]

    char* ws = (char*)d_ws;
    unsigned long long* buf0 = (unsigned long long*)ws;            // 16 KB
    unsigned long long* buf1 = (unsigned long long*)(ws + RSIZE * 8);

    // init tagged buffers (ws is poisoned 0xAA before every timed launch)
    init_ws_kernel<<<8, 256, 0, stream>>>(buf0, buf1);

    // x-part of the output, independent of the recurrence
    {
        int n = (T_STEPS - WARMUP) * ISIZE;
        xcopy_kernel<<<(n + 255) / 256, 256, 0, stream>>>(x, out);
    }

    // the sequential scan: 128 persistent workgroups (1 per CU)
    esn_scan_kernel<<<NWG, 256, 0, stream>>>(x, Win, Wh, out, buf0, buf1);
}